// Round 1
// baseline (8718.962 us; speedup 1.0000x reference)
//
#include <hip/hip_runtime.h>
#include <math.h>

#define NN 2
#define CC 512
#define PP 6272   // T*H*W
static const size_t NCP = (size_t)NN * CC * PP;   // 6,422,528

// ---------------------------------------------------------------------------
// K1: 1x1 conv as GEMM: out[n,co,p] = bias[co] + sum_ci W[co,ci]*in[n,ci,p]
// grid (PP/64, CC/64, NN), block 256, 64x64 tile, 4x4 micro, KTILE=32
// ---------------------------------------------------------------------------
__global__ __launch_bounds__(256) void k_conv(const float* __restrict__ W,
                                              const float* __restrict__ bias,
                                              const float* __restrict__ in,
                                              float* __restrict__ out) {
  __shared__ float Ws[32][68];   // [ci][co]
  __shared__ float Xs[32][68];   // [ci][p]
  const int tid = threadIdx.x;
  const int p0  = blockIdx.x * 64;
  const int co0 = blockIdx.y * 64;
  const size_t nbase = (size_t)blockIdx.z * CC * PP;
  const int tx = tid & 15, ty = tid >> 4;
  float acc[4][4] = {};
  for (int k0 = 0; k0 < CC; k0 += 32) {
#pragma unroll
    for (int q = 0; q < 2; ++q) {
      int slot = q * 256 + tid;           // 512 float4 slots each
      {
        int co_l = slot >> 3, ci4 = (slot & 7) << 2;
        float4 w4 = *(const float4*)&W[(size_t)(co0 + co_l) * CC + k0 + ci4];
        Ws[ci4 + 0][co_l] = w4.x;
        Ws[ci4 + 1][co_l] = w4.y;
        Ws[ci4 + 2][co_l] = w4.z;
        Ws[ci4 + 3][co_l] = w4.w;
      }
      {
        int row = slot >> 4, p4 = (slot & 15) << 2;
        *(float4*)&Xs[row][p4] =
            *(const float4*)&in[nbase + (size_t)(k0 + row) * PP + p0 + p4];
      }
    }
    __syncthreads();
#pragma unroll
    for (int kk = 0; kk < 32; ++kk) {
      float4 a = *(const float4*)&Ws[kk][ty * 4];
      float4 b = *(const float4*)&Xs[kk][tx * 4];
      acc[0][0] += a.x * b.x; acc[0][1] += a.x * b.y; acc[0][2] += a.x * b.z; acc[0][3] += a.x * b.w;
      acc[1][0] += a.y * b.x; acc[1][1] += a.y * b.y; acc[1][2] += a.y * b.z; acc[1][3] += a.y * b.w;
      acc[2][0] += a.z * b.x; acc[2][1] += a.z * b.y; acc[2][2] += a.z * b.z; acc[2][3] += a.z * b.w;
      acc[3][0] += a.w * b.x; acc[3][1] += a.w * b.y; acc[3][2] += a.w * b.z; acc[3][3] += a.w * b.w;
    }
    __syncthreads();
  }
#pragma unroll
  for (int i = 0; i < 4; ++i) {
    int co = co0 + ty * 4 + i;
    float bv = bias[co];
    float4 v = make_float4(acc[i][0] + bv, acc[i][1] + bv, acc[i][2] + bv, acc[i][3] + bv);
    *(float4*)&out[nbase + (size_t)co * PP + p0 + tx * 4] = v;
  }
}

// ---------------------------------------------------------------------------
// K2 (pass A): per-row max m and sum Z of softmax over energy[n,t,:]
// energy[t,s] = sum_c phx[c,t]*pg[c,s].  TQ=32, TS=64, KTILE=64.
// grid (PP/32, NN), block 256; micro 2t x 4s per thread.
// ---------------------------------------------------------------------------
__global__ __launch_bounds__(256) void k_passA(const float* __restrict__ phx,
                                               const float* __restrict__ pg,
                                               float* __restrict__ mQ,
                                               float* __restrict__ Zq) {
  __shared__ float As[64][36];   // [c][t]  32 t
  __shared__ float Bs[64][68];   // [c][s]  64 s
  __shared__ float redm[32][17];
  __shared__ float redz[32][17];
  const int tid = threadIdx.x;
  const int t0 = blockIdx.x * 32;
  const size_t nbase = (size_t)blockIdx.y * CC * PP;
  const int tx = tid & 15, ty = tid >> 4;
  float m0 = -INFINITY, m1 = -INFINITY, z0 = 0.f, z1 = 0.f;
  for (int s0 = 0; s0 < PP; s0 += 64) {
    float e[2][4] = {};
    for (int k0 = 0; k0 < CC; k0 += 64) {
#pragma unroll
      for (int q = 0; q < 2; ++q) {  // phx tile 64x32
        int slot = q * 256 + tid;
        int row = slot >> 3, c4 = (slot & 7) << 2;
        *(float4*)&As[row][c4] =
            *(const float4*)&phx[nbase + (size_t)(k0 + row) * PP + t0 + c4];
      }
#pragma unroll
      for (int q = 0; q < 4; ++q) {  // pg tile 64x64
        int slot = q * 256 + tid;
        int row = slot >> 4, c4 = (slot & 15) << 2;
        *(float4*)&Bs[row][c4] =
            *(const float4*)&pg[nbase + (size_t)(k0 + row) * PP + s0 + c4];
      }
      __syncthreads();
#pragma unroll 16
      for (int kk = 0; kk < 64; ++kk) {
        float2 a = *(const float2*)&As[kk][tx * 2];
        float4 b = *(const float4*)&Bs[kk][ty * 4];
        e[0][0] += a.x * b.x; e[0][1] += a.x * b.y; e[0][2] += a.x * b.z; e[0][3] += a.x * b.w;
        e[1][0] += a.y * b.x; e[1][1] += a.y * b.y; e[1][2] += a.y * b.z; e[1][3] += a.y * b.w;
      }
      __syncthreads();
    }
    {
      float em = fmaxf(fmaxf(e[0][0], e[0][1]), fmaxf(e[0][2], e[0][3]));
      float nm = fmaxf(m0, em);
      z0 = z0 * __expf(m0 - nm) + __expf(e[0][0] - nm) + __expf(e[0][1] - nm) +
           __expf(e[0][2] - nm) + __expf(e[0][3] - nm);
      m0 = nm;
    }
    {
      float em = fmaxf(fmaxf(e[1][0], e[1][1]), fmaxf(e[1][2], e[1][3]));
      float nm = fmaxf(m1, em);
      z1 = z1 * __expf(m1 - nm) + __expf(e[1][0] - nm) + __expf(e[1][1] - nm) +
           __expf(e[1][2] - nm) + __expf(e[1][3] - nm);
      m1 = nm;
    }
  }
  redm[tx * 2 + 0][ty] = m0; redz[tx * 2 + 0][ty] = z0;
  redm[tx * 2 + 1][ty] = m1; redz[tx * 2 + 1][ty] = z1;
  __syncthreads();
  if (tid < 32) {
    float m = -INFINITY;
#pragma unroll
    for (int g = 0; g < 16; ++g) m = fmaxf(m, redm[tid][g]);
    float z = 0.f;
#pragma unroll
    for (int g = 0; g < 16; ++g) z += redz[tid][g] * __expf(redm[tid][g] - m);
    mQ[(size_t)blockIdx.y * PP + t0 + tid] = m;
    Zq[(size_t)blockIdx.y * PP + t0 + tid] = z;
  }
}

// ---------------------------------------------------------------------------
// K3 (pass B): me[n,c,t] = sum_s phm[n,c,s] * exp(energy[t,s]-m_t)/Z_t
// Per block: one n, 32 t.  Loop s in tiles of 64: recompute E tile, form p
// in LDS, rank-update me accumulator (512c x 32t held in registers across
// the block: 4 chunks x 2c x 8t per thread).
// ---------------------------------------------------------------------------
__global__ __launch_bounds__(256) void k_passB(const float* __restrict__ phx,
                                               const float* __restrict__ pg,
                                               const float* __restrict__ phm,
                                               const float* __restrict__ mQ,
                                               const float* __restrict__ Zq,
                                               float* __restrict__ me) {
  __shared__ float As[64][36];    // [c][t]
  __shared__ float Bs[64][68];    // [c][s]
  __shared__ float Ps[64][36];    // [s][t]
  __shared__ float Ms[128][66];   // phm chunk [c][s]
  const int tid = threadIdx.x;
  const int t0 = blockIdx.x * 32;
  const int n = blockIdx.y;
  const size_t nbase = (size_t)n * CC * PP;
  const int tx = tid & 15, ty = tid >> 4;
  const int tb = (tid & 3) * 8;     // t base for ME phase (8 t's)
  const int cg2 = (tid >> 2) * 2;   // c pair within chunk

  float mq[2], rzq[2];
#pragma unroll
  for (int ii = 0; ii < 2; ++ii) {
    mq[ii] = mQ[(size_t)n * PP + t0 + tx * 2 + ii];
    rzq[ii] = 1.0f / Zq[(size_t)n * PP + t0 + tx * 2 + ii];
  }

  float acc[4][2][8] = {};

  for (int s0 = 0; s0 < PP; s0 += 64) {
    // ---- E tile (32t x 64s) ----
    float e[2][4] = {};
    for (int k0 = 0; k0 < CC; k0 += 64) {
#pragma unroll
      for (int q = 0; q < 2; ++q) {
        int slot = q * 256 + tid;
        int row = slot >> 3, c4 = (slot & 7) << 2;
        *(float4*)&As[row][c4] =
            *(const float4*)&phx[nbase + (size_t)(k0 + row) * PP + t0 + c4];
      }
#pragma unroll
      for (int q = 0; q < 4; ++q) {
        int slot = q * 256 + tid;
        int row = slot >> 4, c4 = (slot & 15) << 2;
        *(float4*)&Bs[row][c4] =
            *(const float4*)&pg[nbase + (size_t)(k0 + row) * PP + s0 + c4];
      }
      __syncthreads();
#pragma unroll 16
      for (int kk = 0; kk < 64; ++kk) {
        float2 a = *(const float2*)&As[kk][tx * 2];
        float4 b = *(const float4*)&Bs[kk][ty * 4];
        e[0][0] += a.x * b.x; e[0][1] += a.x * b.y; e[0][2] += a.x * b.z; e[0][3] += a.x * b.w;
        e[1][0] += a.y * b.x; e[1][1] += a.y * b.y; e[1][2] += a.y * b.z; e[1][3] += a.y * b.w;
      }
      __syncthreads();
    }
    // ---- p = exp(e - m)/Z into LDS (layout [s][t]) ----
#pragma unroll
    for (int ii = 0; ii < 2; ++ii)
#pragma unroll
      for (int jj = 0; jj < 4; ++jj)
        Ps[ty * 4 + jj][tx * 2 + ii] = __expf(e[ii][jj] - mq[ii]) * rzq[ii];
    // ---- ME: me[c,t] += phm[c,s] * p[t,s], c chunked by 128 ----
#pragma unroll
    for (int ch = 0; ch < 4; ++ch) {
#pragma unroll
      for (int q = 0; q < 8; ++q) {   // load 128x64 chunk of phm
        int slot = q * 256 + tid;
        int c_l = slot >> 4, s4 = (slot & 15) << 2;
        float4 v = *(const float4*)&phm[nbase + (size_t)(ch * 128 + c_l) * PP + s0 + s4];
        *(float2*)&Ms[c_l][s4]     = make_float2(v.x, v.y);
        *(float2*)&Ms[c_l][s4 + 2] = make_float2(v.z, v.w);
      }
      __syncthreads();
#pragma unroll 4
      for (int s = 0; s < 64; ++s) {
        float a0 = Ms[cg2][s];
        float a1 = Ms[cg2 + 1][s];
        float4 pA = *(const float4*)&Ps[s][tb];
        float4 pB = *(const float4*)&Ps[s][tb + 4];
        acc[ch][0][0] += a0 * pA.x; acc[ch][0][1] += a0 * pA.y;
        acc[ch][0][2] += a0 * pA.z; acc[ch][0][3] += a0 * pA.w;
        acc[ch][0][4] += a0 * pB.x; acc[ch][0][5] += a0 * pB.y;
        acc[ch][0][6] += a0 * pB.z; acc[ch][0][7] += a0 * pB.w;
        acc[ch][1][0] += a1 * pA.x; acc[ch][1][1] += a1 * pA.y;
        acc[ch][1][2] += a1 * pA.z; acc[ch][1][3] += a1 * pA.w;
        acc[ch][1][4] += a1 * pB.x; acc[ch][1][5] += a1 * pB.y;
        acc[ch][1][6] += a1 * pB.z; acc[ch][1][7] += a1 * pB.w;
      }
      __syncthreads();
    }
  }
  // epilogue: write me
#pragma unroll
  for (int ch = 0; ch < 4; ++ch)
#pragma unroll
    for (int cc = 0; cc < 2; ++cc) {
      int c = ch * 128 + cg2 + cc;
      float* dst = &me[nbase + (size_t)c * PP + t0 + tb];
      *(float4*)&dst[0] = make_float4(acc[ch][cc][0], acc[ch][cc][1], acc[ch][cc][2], acc[ch][cc][3]);
      *(float4*)&dst[4] = make_float4(acc[ch][cc][4], acc[ch][cc][5], acc[ch][cc][6], acc[ch][cc][7]);
    }
}

// ---------------------------------------------------------------------------
// K4a: row softmax stats of me over last axis (per n,c): m2, Z2
// ---------------------------------------------------------------------------
__global__ __launch_bounds__(256) void k_soft2(const float* __restrict__ me,
                                               float* __restrict__ m2,
                                               float* __restrict__ Z2) {
  __shared__ float red[256];
  const float* row = me + (size_t)blockIdx.x * PP;
  const int tid = threadIdx.x;
  float m = -INFINITY;
  for (int i = tid; i < PP; i += 256) m = fmaxf(m, row[i]);
  red[tid] = m;
  __syncthreads();
  for (int s = 128; s > 0; s >>= 1) {
    if (tid < s) red[tid] = fmaxf(red[tid], red[tid + s]);
    __syncthreads();
  }
  m = red[0];
  __syncthreads();
  float z = 0.f;
  for (int i = tid; i < PP; i += 256) z += __expf(row[i] - m);
  red[tid] = z;
  __syncthreads();
  for (int s = 128; s > 0; s >>= 1) {
    if (tid < s) red[tid] += red[tid + s];
    __syncthreads();
  }
  if (tid == 0) { m2[blockIdx.x] = m; Z2[blockIdx.x] = red[0]; }
}

// ---------------------------------------------------------------------------
// K4b: BatchNorm stats per channel over (N, THW)
// ---------------------------------------------------------------------------
__global__ __launch_bounds__(256) void k_bnstat(const float* __restrict__ wz,
                                                float* __restrict__ mu,
                                                float* __restrict__ rinv) {
  __shared__ float rs[256];
  __shared__ float rq[256];
  const int c = blockIdx.x;
  const int tid = threadIdx.x;
  float s = 0.f, q = 0.f;
  for (int n = 0; n < NN; ++n) {
    const float* rowp = wz + (size_t)n * CC * PP + (size_t)c * PP;
    for (int p = tid; p < PP; p += 256) {
      float v = rowp[p];
      s += v;
      q += v * v;
    }
  }
  rs[tid] = s; rq[tid] = q;
  __syncthreads();
  for (int st = 128; st > 0; st >>= 1) {
    if (tid < st) { rs[tid] += rs[tid + st]; rq[tid] += rq[tid + st]; }
    __syncthreads();
  }
  if (tid == 0) {
    const float inv_n = 1.0f / (float)(NN * PP);
    float mean = rs[0] * inv_n;
    float var = rq[0] * inv_n - mean * mean;
    mu[c] = mean;
    rinv[c] = rsqrtf(var + 1e-5f);
  }
}

// ---------------------------------------------------------------------------
// K5: out = gamma * pm * softmax2(me) + BN(wz)
// ---------------------------------------------------------------------------
__global__ __launch_bounds__(256) void k_final(const float* __restrict__ pm,
                                               const float* __restrict__ me,
                                               const float* __restrict__ wz,
                                               const float* __restrict__ m2,
                                               const float* __restrict__ Z2,
                                               const float* __restrict__ mu,
                                               const float* __restrict__ rinv,
                                               const float* __restrict__ bnw,
                                               const float* __restrict__ bnb,
                                               const float* __restrict__ gamma,
                                               float* __restrict__ out) {
  const int e4 = blockIdx.x * 256 + threadIdx.x;
  const size_t e = (size_t)e4 * 4;
  const int nc = (int)(e / PP);
  const int c = nc & (CC - 1);
  const float m = m2[nc];
  const float rz = 1.0f / Z2[nc];
  const float mub = mu[c];
  const float ri = rinv[c] * bnw[c];
  const float bb = bnb[c];
  const float g = gamma[0];
  float4 pmv = *(const float4*)&pm[e];
  float4 mev = *(const float4*)&me[e];
  float4 wzv = *(const float4*)&wz[e];
  float4 o;
  o.x = g * pmv.x * (__expf(mev.x - m) * rz) + (wzv.x - mub) * ri + bb;
  o.y = g * pmv.y * (__expf(mev.y - m) * rz) + (wzv.y - mub) * ri + bb;
  o.z = g * pmv.z * (__expf(mev.z - m) * rz) + (wzv.z - mub) * ri + bb;
  o.w = g * pmv.w * (__expf(mev.w - m) * rz) + (wzv.w - mub) * ri + bb;
  *(float4*)&out[e] = o;
}

// ---------------------------------------------------------------------------
extern "C" void kernel_launch(void* const* d_in, const int* in_sizes, int n_in,
                              void* d_out, int out_size, void* d_ws, size_t ws_size,
                              hipStream_t stream) {
  (void)in_sizes; (void)n_in; (void)out_size; (void)ws_size;
  const float* x    = (const float*)d_in[0];
  const float* mask = (const float*)d_in[1];
  const float* Wh   = (const float*)d_in[2];
  const float* bh   = (const float*)d_in[3];
  const float* Wg   = (const float*)d_in[4];
  const float* bg   = (const float*)d_in[5];
  const float* Wm   = (const float*)d_in[6];
  const float* bm   = (const float*)d_in[7];
  const float* Wz   = (const float*)d_in[8];
  const float* bz   = (const float*)d_in[9];
  const float* bnw  = (const float*)d_in[10];
  const float* bnb  = (const float*)d_in[11];
  const float* gam  = (const float*)d_in[12];

  float* ws  = (float*)d_ws;
  float* phx = ws;
  float* pg  = ws + 1 * NCP;
  float* phm = ws + 2 * NCP;
  float* pmb = ws + 3 * NCP;
  float* wz  = ws + 4 * NCP;
  float* me  = ws + 5 * NCP;
  float* mQ  = ws + 6 * NCP;
  float* Zq  = mQ + (size_t)NN * PP;
  float* m2  = Zq + (size_t)NN * PP;
  float* Z2  = m2 + (size_t)NN * CC;
  float* mu  = Z2 + (size_t)NN * CC;
  float* rin = mu + CC;

  dim3 gconv(PP / 64, CC / 64, NN);
  k_conv<<<gconv, 256, 0, stream>>>(Wh, bh, x, phx);
  k_conv<<<gconv, 256, 0, stream>>>(Wg, bg, x, pg);
  k_conv<<<gconv, 256, 0, stream>>>(Wh, bh, mask, phm);
  k_conv<<<gconv, 256, 0, stream>>>(Wm, bm, x, pmb);
  k_conv<<<gconv, 256, 0, stream>>>(Wz, bz, x, wz);

  dim3 gflash(PP / 32, NN);
  k_passA<<<gflash, 256, 0, stream>>>(phx, pg, mQ, Zq);
  k_passB<<<gflash, 256, 0, stream>>>(phx, pg, phm, mQ, Zq, me);

  k_soft2<<<NN * CC, 256, 0, stream>>>(me, m2, Z2);
  k_bnstat<<<CC, 256, 0, stream>>>(wz, mu, rin);

  const int total4 = (int)(NCP / 4);
  k_final<<<total4 / 256, 256, 0, stream>>>(pmb, me, wz, m2, Z2, mu, rin,
                                            bnw, bnb, gam, (float*)d_out);
}

// Round 3
// 1027.478 us; speedup vs baseline: 8.4858x; 8.4858x over previous
//
#include <hip/hip_runtime.h>
#include <hip/hip_bf16.h>
#include <math.h>

#define NN 2
#define CC 512
#define PP 6272            // T*H*W
#define TCH 896            // t-chunk rows (7 chunks x 7 tiles of 128)
#define NCHK 7
static const size_t PPC = (size_t)PP * CC;   // per-n projection elems
static const size_t NCP = (size_t)NN * PPC;  // 6,422,528

typedef unsigned short ushortT;
typedef __attribute__((ext_vector_type(8))) short short8;   // 8 bf16 = 4 VGPR
typedef __attribute__((ext_vector_type(4))) float f32x4;

__device__ __forceinline__ ushortT f2bf(float f) {
  __hip_bfloat16 h = __float2bfloat16(f);
  return *reinterpret_cast<ushortT*>(&h);
}
__device__ __forceinline__ float bf2f(ushortT u) {
  return __uint_as_float(((unsigned)u) << 16);
}

// async global->LDS, 16B/lane. LDS dest = wave-uniform base + lane*16.
__device__ __forceinline__ void ld_g2l(const void* g, void* l) {
  __builtin_amdgcn_global_load_lds(
      (const __attribute__((address_space(1))) void*)g,
      (__attribute__((address_space(3))) void*)l, 16, 0, 0);
}

// ---------------------------------------------------------------------------
// flat fp32 -> bf16 cast (for 512x512 weights): 256 blocks x 256 thr x 4 elems
// ---------------------------------------------------------------------------
__global__ __launch_bounds__(256) void k_cast(const float* __restrict__ src,
                                              ushortT* __restrict__ dst) {
  const int i = (blockIdx.x * 256 + threadIdx.x) * 4;
  float4 v = *(const float4*)&src[i];
  ushort4 o;
  o.x = f2bf(v.x); o.y = f2bf(v.y); o.z = f2bf(v.z); o.w = f2bf(v.w);
  *(ushort4*)&dst[i] = o;
}

// ---------------------------------------------------------------------------
// transpose-cast: in fp32 [n][c][p] -> out bf16 [n][p][c].  32x32 tiles.
// ---------------------------------------------------------------------------
__global__ void k_castT(const float* __restrict__ in, ushortT* __restrict__ out) {
  __shared__ float T[32][33];
  const int p0 = blockIdx.x * 32, c0 = blockIdx.y * 32;
  const int tx = threadIdx.x, ty = threadIdx.y;
  const size_t nbi = (size_t)blockIdx.z * PPC;
#pragma unroll
  for (int i = 0; i < 4; ++i)
    T[ty + i * 8][tx] = in[nbi + (size_t)(c0 + ty + i * 8) * PP + p0 + tx];
  __syncthreads();
#pragma unroll
  for (int i = 0; i < 4; ++i) {
    int r = ty + i * 8;
    out[nbi + (size_t)(p0 + r) * CC + c0 + tx] = f2bf(T[tx][r]);
  }
}

// ---------------------------------------------------------------------------
// BT-GEMM: D[i,j] = sum_k A[i,k]*B[j,k] (+bias), 128x128 tile, BK=64, MFMA.
// OM 0: bf16 out, bias[j] | OM 1: bf16 out, bias[i] | OM 2: f32 out, bias[i]
// OM 3: f32 out, no bias (energy chunks)
// grid: (J/128, I/128, NN); per-z strides sAn/sBn/sOn; out leading dim ldo.
// ---------------------------------------------------------------------------
template <int OM>
__global__ __launch_bounds__(256) void k_bgemm(const ushortT* __restrict__ A,
                                               const ushortT* __restrict__ B,
                                               const float* __restrict__ bias,
                                               void* __restrict__ outv,
                                               int KD, size_t sAn, size_t sBn,
                                               size_t sOn, int ldo) {
  __shared__ __align__(16) ushortT At[128 * 64];
  __shared__ __align__(16) ushortT Bt[128 * 64];
  const int tid = threadIdx.x;
  const int l = tid & 63, w = tid >> 6;
  const int j0 = blockIdx.x * 128;
  const int i0 = blockIdx.y * 128;
  A += (size_t)blockIdx.z * sAn;
  B += (size_t)blockIdx.z * sBn;
  const int wi = (w & 1) * 64, wj = (w >> 1) * 64;
  const int lr = l & 15, lk = l >> 4;
  const int sr = l >> 3, scg = l & 7;

  f32x4 acc[4][4] = {};

  for (int k0 = 0; k0 < KD; k0 += 64) {
#pragma unroll
    for (int i = 0; i < 4; ++i) {
      int row = w * 32 + i * 8 + sr;
      int cs = scg ^ (row & 7);
      ld_g2l(A + (size_t)(i0 + row) * KD + k0 + cs * 8, (char*)At + (w * 4 + i) * 1024);
      ld_g2l(B + (size_t)(j0 + row) * KD + k0 + cs * 8, (char*)Bt + (w * 4 + i) * 1024);
    }
    __syncthreads();
#pragma unroll
    for (int ks = 0; ks < 2; ++ks) {
      short8 af[4], bfv[4];
      const int cc = ks * 4 + lk;
#pragma unroll
      for (int tt = 0; tt < 4; ++tt) {
        int row = wi + tt * 16 + lr;
        af[tt] = *(const short8*)((const char*)At + row * 128 + ((cc ^ (row & 7)) * 16));
      }
#pragma unroll
      for (int ss = 0; ss < 4; ++ss) {
        int row = wj + ss * 16 + lr;
        bfv[ss] = *(const short8*)((const char*)Bt + row * 128 + ((cc ^ (row & 7)) * 16));
      }
#pragma unroll
      for (int tt = 0; tt < 4; ++tt)
#pragma unroll
        for (int ss = 0; ss < 4; ++ss)
          acc[tt][ss] = __builtin_amdgcn_mfma_f32_16x16x32_bf16(af[tt], bfv[ss], acc[tt][ss], 0, 0, 0);
    }
    __syncthreads();
  }
  const int r4 = (l >> 4) * 4;
  if (OM == 0) {
    ushortT* out = (ushortT*)outv + (size_t)blockIdx.z * sOn;
    float bj[4];
#pragma unroll
    for (int ss = 0; ss < 4; ++ss) bj[ss] = bias[j0 + wj + ss * 16 + lr];
#pragma unroll
    for (int tt = 0; tt < 4; ++tt)
#pragma unroll
      for (int r = 0; r < 4; ++r) {
        int i = i0 + wi + tt * 16 + r4 + r;
#pragma unroll
        for (int ss = 0; ss < 4; ++ss) {
          int j = j0 + wj + ss * 16 + lr;
          out[(size_t)i * ldo + j] = f2bf(acc[tt][ss][r] + bj[ss]);
        }
      }
  } else if (OM == 1) {
    ushortT* out = (ushortT*)outv + (size_t)blockIdx.z * sOn;
#pragma unroll
    for (int tt = 0; tt < 4; ++tt)
#pragma unroll
      for (int r = 0; r < 4; ++r) {
        int i = i0 + wi + tt * 16 + r4 + r;
        float bi = bias[i];
#pragma unroll
        for (int ss = 0; ss < 4; ++ss) {
          int j = j0 + wj + ss * 16 + lr;
          out[(size_t)i * ldo + j] = f2bf(acc[tt][ss][r] + bi);
        }
      }
  } else if (OM == 2) {
    float* out = (float*)outv + (size_t)blockIdx.z * sOn;
#pragma unroll
    for (int tt = 0; tt < 4; ++tt)
#pragma unroll
      for (int r = 0; r < 4; ++r) {
        int i = i0 + wi + tt * 16 + r4 + r;
        float bi = bias[i];
#pragma unroll
        for (int ss = 0; ss < 4; ++ss) {
          int j = j0 + wj + ss * 16 + lr;
          out[(size_t)i * ldo + j] = acc[tt][ss][r] + bi;
        }
      }
  } else {
    float* out = (float*)outv + (size_t)blockIdx.z * sOn;
#pragma unroll
    for (int tt = 0; tt < 4; ++tt)
#pragma unroll
      for (int r = 0; r < 4; ++r) {
        int i = i0 + wi + tt * 16 + r4 + r;
#pragma unroll
        for (int ss = 0; ss < 4; ++ss) {
          int j = j0 + wj + ss * 16 + lr;
          out[(size_t)i * ldo + j] = acc[tt][ss][r];
        }
      }
  }
}

// ---------------------------------------------------------------------------
// softmax row of fp32 E chunk -> bf16 P packed in place (low half of row).
// All global reads complete before any write (reduction barriers separate).
// grid: NN*TCH blocks; row = Ech + blockIdx.x*PP (fp32).
// ---------------------------------------------------------------------------
__global__ __launch_bounds__(256) void k_softmaxP(float* __restrict__ Ech) {
  __shared__ float red[256];
  float* R = Ech + (size_t)blockIdx.x * PP;
  const int tid = threadIdx.x;
  float v[25];
  int cnt = 0;
  float m = -INFINITY;
  for (int i = tid; i < PP; i += 256) {
    v[cnt] = R[i];
    m = fmaxf(m, v[cnt]);
    ++cnt;
  }
  red[tid] = m;
  __syncthreads();
  for (int s = 128; s > 0; s >>= 1) {
    if (tid < s) red[tid] = fmaxf(red[tid], red[tid + s]);
    __syncthreads();
  }
  m = red[0];
  __syncthreads();
  float z = 0.f;
  for (int q = 0; q < cnt; ++q) {
    v[q] = __expf(v[q] - m);
    z += v[q];
  }
  red[tid] = z;
  __syncthreads();
  for (int s = 128; s > 0; s >>= 1) {
    if (tid < s) red[tid] += red[tid + s];
    __syncthreads();
  }
  const float rz = 1.0f / red[0];
  ushortT* O = (ushortT*)R;
  cnt = 0;
  for (int i = tid; i < PP; i += 256) {
    O[i] = f2bf(v[cnt] * rz);
    ++cnt;
  }
}

// ---------------------------------------------------------------------------
// me[n,c,tbase+tl] = sum_s phm[n,c,s] * P[n,tl,s]   (64x64 tile, BK=64)
// P is bf16 packed at start of fp32 rows (row byte stride PP*4).
// grid (TCH/64, CC/64, NN).
// ---------------------------------------------------------------------------
__global__ __launch_bounds__(256) void k_me(const ushortT* __restrict__ phmB,
                                            const float* __restrict__ Ech,
                                            float* __restrict__ me, int tbase) {
  __shared__ __align__(16) ushortT Am[64 * 64];
  __shared__ __align__(16) ushortT Bp[64 * 64];
  const int tid = threadIdx.x;
  const int l = tid & 63, w = tid >> 6;
  const int tl0 = blockIdx.x * 64;
  const int c0 = blockIdx.y * 64;
  const int z = blockIdx.z;
  const size_t nb = (size_t)z * CC * PP;
  const char* Pbase = (const char*)Ech + (size_t)z * TCH * PP * 4;
  const int wc = (w & 1) * 32, wt2 = (w >> 1) * 32;
  const int lr = l & 15, lk = l >> 4;
  const int sr = l >> 3, scg = l & 7;

  f32x4 acc[2][2] = {};

  for (int s0 = 0; s0 < PP; s0 += 64) {
#pragma unroll
    for (int i = 0; i < 2; ++i) {
      int row = w * 16 + i * 8 + sr;
      int cs = scg ^ (row & 7);
      ld_g2l(phmB + nb + (size_t)(c0 + row) * PP + s0 + cs * 8, (char*)Am + (w * 2 + i) * 1024);
      ld_g2l(Pbase + (size_t)(tl0 + row) * PP * 4 + (size_t)(s0 + cs * 8) * 2,
             (char*)Bp + (w * 2 + i) * 1024);
    }
    __syncthreads();
#pragma unroll
    for (int ks = 0; ks < 2; ++ks) {
      short8 af[2], bfv[2];
      const int cc = ks * 4 + lk;
#pragma unroll
      for (int ct = 0; ct < 2; ++ct) {
        int row = wc + ct * 16 + lr;
        af[ct] = *(const short8*)((const char*)Am + row * 128 + ((cc ^ (row & 7)) * 16));
      }
#pragma unroll
      for (int tt = 0; tt < 2; ++tt) {
        int row = wt2 + tt * 16 + lr;
        bfv[tt] = *(const short8*)((const char*)Bp + row * 128 + ((cc ^ (row & 7)) * 16));
      }
#pragma unroll
      for (int ct = 0; ct < 2; ++ct)
#pragma unroll
        for (int tt = 0; tt < 2; ++tt)
          acc[ct][tt] = __builtin_amdgcn_mfma_f32_16x16x32_bf16(af[ct], bfv[tt], acc[ct][tt], 0, 0, 0);
    }
    __syncthreads();
  }
  const int r4 = (l >> 4) * 4;
#pragma unroll
  for (int ct = 0; ct < 2; ++ct)
#pragma unroll
    for (int tt = 0; tt < 2; ++tt)
#pragma unroll
      for (int r = 0; r < 4; ++r) {
        int c = c0 + wc + ct * 16 + r4 + r;
        int t = tbase + tl0 + wt2 + tt * 16 + lr;
        me[nb + (size_t)c * PP + t] = acc[ct][tt][r];
      }
}

// ---------------------------------------------------------------------------
__global__ __launch_bounds__(256) void k_soft2(const float* __restrict__ me,
                                               float* __restrict__ m2,
                                               float* __restrict__ Z2) {
  __shared__ float red[256];
  const float* row = me + (size_t)blockIdx.x * PP;
  const int tid = threadIdx.x;
  float m = -INFINITY;
  for (int i = tid; i < PP; i += 256) m = fmaxf(m, row[i]);
  red[tid] = m;
  __syncthreads();
  for (int s = 128; s > 0; s >>= 1) {
    if (tid < s) red[tid] = fmaxf(red[tid], red[tid + s]);
    __syncthreads();
  }
  m = red[0];
  __syncthreads();
  float z = 0.f;
  for (int i = tid; i < PP; i += 256) z += __expf(row[i] - m);
  red[tid] = z;
  __syncthreads();
  for (int s = 128; s > 0; s >>= 1) {
    if (tid < s) red[tid] += red[tid + s];
    __syncthreads();
  }
  if (tid == 0) { m2[blockIdx.x] = m; Z2[blockIdx.x] = red[0]; }
}

__global__ __launch_bounds__(256) void k_bnstat(const float* __restrict__ wz,
                                                float* __restrict__ mu,
                                                float* __restrict__ rinv) {
  __shared__ float rs[256];
  __shared__ float rq[256];
  const int c = blockIdx.x;
  const int tid = threadIdx.x;
  float s = 0.f, q = 0.f;
  for (int n = 0; n < NN; ++n) {
    const float* rowp = wz + (size_t)n * CC * PP + (size_t)c * PP;
    for (int p = tid; p < PP; p += 256) {
      float v = rowp[p];
      s += v;
      q += v * v;
    }
  }
  rs[tid] = s; rq[tid] = q;
  __syncthreads();
  for (int st = 128; st > 0; st >>= 1) {
    if (tid < st) { rs[tid] += rs[tid + st]; rq[tid] += rq[tid + st]; }
    __syncthreads();
  }
  if (tid == 0) {
    const float inv_n = 1.0f / (float)(NN * PP);
    float mean = rs[0] * inv_n;
    float var = rq[0] * inv_n - mean * mean;
    mu[c] = mean;
    rinv[c] = rsqrtf(var + 1e-5f);
  }
}

__global__ __launch_bounds__(256) void k_final(const ushortT* __restrict__ pmB,
                                               const float* __restrict__ me,
                                               const float* __restrict__ wz,
                                               const float* __restrict__ m2,
                                               const float* __restrict__ Z2,
                                               const float* __restrict__ mu,
                                               const float* __restrict__ rinv,
                                               const float* __restrict__ bnw,
                                               const float* __restrict__ bnb,
                                               const float* __restrict__ gamma,
                                               float* __restrict__ out) {
  const int e4 = blockIdx.x * 256 + threadIdx.x;
  const size_t e = (size_t)e4 * 4;
  const int nc = (int)(e / PP);
  const int c = nc & (CC - 1);
  const float m = m2[nc];
  const float rz = 1.0f / Z2[nc];
  const float mub = mu[c];
  const float ri = rinv[c] * bnw[c];
  const float bb = bnb[c];
  const float g = gamma[0];
  ushort4 pv = *(const ushort4*)&pmB[e];
  float4 mev = *(const float4*)&me[e];
  float4 wzv = *(const float4*)&wz[e];
  float4 o;
  o.x = g * bf2f(pv.x) * (__expf(mev.x - m) * rz) + (wzv.x - mub) * ri + bb;
  o.y = g * bf2f(pv.y) * (__expf(mev.y - m) * rz) + (wzv.y - mub) * ri + bb;
  o.z = g * bf2f(pv.z) * (__expf(mev.z - m) * rz) + (wzv.z - mub) * ri + bb;
  o.w = g * bf2f(pv.w) * (__expf(mev.w - m) * rz) + (wzv.w - mub) * ri + bb;
  *(float4*)&out[e] = o;
}

// ---------------------------------------------------------------------------
extern "C" void kernel_launch(void* const* d_in, const int* in_sizes, int n_in,
                              void* d_out, int out_size, void* d_ws, size_t ws_size,
                              hipStream_t stream) {
  (void)in_sizes; (void)n_in; (void)out_size; (void)ws_size;
  const float* x    = (const float*)d_in[0];
  const float* mask = (const float*)d_in[1];
  const float* Wh   = (const float*)d_in[2];
  const float* bh   = (const float*)d_in[3];
  const float* Wg   = (const float*)d_in[4];
  const float* bg   = (const float*)d_in[5];
  const float* Wm   = (const float*)d_in[6];
  const float* bm   = (const float*)d_in[7];
  const float* Wz   = (const float*)d_in[8];
  const float* bz   = (const float*)d_in[9];
  const float* bnw  = (const float*)d_in[10];
  const float* bnb  = (const float*)d_in[11];
  const float* gam  = (const float*)d_in[12];

  // ---- workspace layout (~149.8 MB total) ----
  float* wzb = (float*)d_ws;                 // fp32 [n][c][p]
  float* meb = wzb + NCP;                    // fp32 [n][c][t]
  ushortT* u    = (ushortT*)(meb + NCP);
  ushortT* pmB  = u;                         // bf16 [n][c][p]
  ushortT* phxT = pmB + NCP;                 // bf16 [n][t][c]
  ushortT* pgT  = phxT + NCP;                // bf16 [n][s][c]
  ushortT* phmB = pgT + NCP;                 // bf16 [n][c][s]
  ushortT* Whbf = phmB + NCP;                // 512x512 bf16 each
  ushortT* Wgbf = Whbf + CC * CC;
  ushortT* Wmbf = Wgbf + CC * CC;
  ushortT* Wzbf = Wmbf + CC * CC;
  float* m2  = (float*)(Wzbf + CC * CC);
  float* Z2  = m2 + NN * CC;
  float* mu  = Z2 + NN * CC;
  float* rin = mu + CC;
  // overlay region: xT/maskT (during convs) then E chunk (fp32, after convs)
  float* region = rin + CC + 4;              // keep 16B alignment
  ushortT* xT    = (ushortT*)region;         // bf16 [n][p][c]
  ushortT* maskT = xT + NCP;
  float* Ech = region;                       // fp32 [n][TCH][PP] chunk

  // ---- casts ----
  k_cast<<<256, 256, 0, stream>>>(Wh, Whbf);
  k_cast<<<256, 256, 0, stream>>>(Wg, Wgbf);
  k_cast<<<256, 256, 0, stream>>>(Wm, Wmbf);
  k_cast<<<256, 256, 0, stream>>>(Wz, Wzbf);
  dim3 gct(PP / 32, CC / 32, NN);
  k_castT<<<gct, dim3(32, 8), 0, stream>>>(x, xT);
  k_castT<<<gct, dim3(32, 8), 0, stream>>>(mask, maskT);

  // ---- 1x1 convs as MFMA BT-GEMMs ----
  dim3 gPc(CC / 128, PP / 128, NN);   // out [p][co]
  k_bgemm<0><<<gPc, 256, 0, stream>>>(xT, Whbf, bh, phxT, CC, PPC, 0, PPC, CC);
  k_bgemm<0><<<gPc, 256, 0, stream>>>(xT, Wgbf, bg, pgT, CC, PPC, 0, PPC, CC);
  dim3 gCp(PP / 128, CC / 128, NN);   // out [co][p]
  k_bgemm<1><<<gCp, 256, 0, stream>>>(Whbf, maskT, bh, phmB, CC, 0, PPC, PPC, PP);
  k_bgemm<1><<<gCp, 256, 0, stream>>>(Wmbf, xT, bm, pmB, CC, 0, PPC, PPC, PP);
  k_bgemm<2><<<gCp, 256, 0, stream>>>(Wzbf, xT, bz, wzb, CC, 0, PPC, PPC, PP);

  // ---- attention: chunked energy -> softmax -> mask_energy ----
  for (int ch = 0; ch < NCHK; ++ch) {
    const int tbase = ch * TCH;
    dim3 gE(PP / 128, TCH / 128, NN);
    k_bgemm<3><<<gE, 256, 0, stream>>>(phxT + (size_t)tbase * CC, pgT, nullptr,
                                       Ech, CC, PPC, PPC, (size_t)TCH * PP, PP);
    k_softmaxP<<<NN * TCH, 256, 0, stream>>>(Ech);
    dim3 gM(TCH / 64, CC / 64, NN);
    k_me<<<gM, 256, 0, stream>>>(phmB, Ech, meb, tbase);
  }

  // ---- tails ----
  k_soft2<<<NN * CC, 256, 0, stream>>>(meb, m2, Z2);
  k_bnstat<<<CC, 256, 0, stream>>>(wzb, mu, rin);
  const int total4 = (int)(NCP / 4);
  k_final<<<total4 / 256, 256, 0, stream>>>(pmB, meb, wzb, m2, Z2, mu, rin,
                                            bnw, bnb, gam, (float*)d_out);
}